// Round 1
// baseline (1433.448 us; speedup 1.0000x reference)
//
#include <hip/hip_runtime.h>
#include <hip/hip_bf16.h>
#include <stdint.h>

// Joint network: out[b,t,u,v] = sum_d tanh(enc[b,t,d]+pred[b,u,d]) * W[v,d] + bias[v]
// B=4 T=256 U=64 D=640 V=4096  ->  GEMM M=65536, N=4096, K=640 (NT: W is [N,K])
#define B_ 4
#define T_ 256
#define U_ 64
#define D_ 640
#define V_ 4096
#define M_ (B_*T_*U_)   // 65536

#define BM 128
#define BN 128
#define BK 64

typedef __attribute__((ext_vector_type(8))) __bf16 bf16x8;
typedef __attribute__((ext_vector_type(4))) float floatx4;

__device__ __forceinline__ unsigned short f2bf(float x) {
  union { float f; uint32_t u; } v; v.f = x;
  uint32_t r = v.u + 0x7fffu + ((v.u >> 16) & 1u);   // RNE
  return (unsigned short)(r >> 16);
}

// tanh(x) = 1 - 2/(e^{2x}+1); exact at +-inf saturation, abs err ~1e-7 (bf16 rounding dominates)
__device__ __forceinline__ float tanh_fast(float x) {
  float e = __expf(2.0f * x);
  return 1.0f - 2.0f / (e + 1.0f);
}

// ---- kernel 1: W fp32 [V,D] -> bf16 bits ----
__global__ void cvt_w(const float* __restrict__ W, ushort* __restrict__ Wb) {
  int i = (blockIdx.x * 256 + threadIdx.x) * 4;      // V*D = 2,621,440, grid covers exactly
  float4 w = *(const float4*)(W + i);
  ushort4 o; o.x = f2bf(w.x); o.y = f2bf(w.y); o.z = f2bf(w.z); o.w = f2bf(w.w);
  *(ushort4*)(Wb + i) = o;
}

// ---- kernel 2: H[m,d] = tanh(enc[m/U, d] + pred[(m/(T*U))*U + m%U, d]) as bf16 ----
__global__ void make_h(const float* __restrict__ enc, const float* __restrict__ pred,
                       ushort* __restrict__ H) {
  int e = blockIdx.x * 256 + threadIdx.x;            // quad id; M*D/4 = 10,485,760
  int m = e / 160;                                   // D/4 = 160
  int d = (e - m * 160) * 4;
  int re = m >> 6;                                   // m / U   -> row in enc (b*T+t)
  int rp = ((m >> 14) << 6) | (m & 63);              // b*U + u -> row in pred
  float4 a = *(const float4*)(enc + (size_t)re * D_ + d);
  float4 p = *(const float4*)(pred + (size_t)rp * D_ + d);
  ushort4 o;
  o.x = f2bf(tanh_fast(a.x + p.x));
  o.y = f2bf(tanh_fast(a.y + p.y));
  o.z = f2bf(tanh_fast(a.z + p.z));
  o.w = f2bf(tanh_fast(a.w + p.w));
  *(ushort4*)(H + (size_t)m * D_ + d) = o;
}

// ---- kernel 3: bf16 NT GEMM, m97 structure (128x128 tile, BK=64, 4 waves of 64x64) ----
__global__ __launch_bounds__(256) void gemm_bt(
    const ushort* __restrict__ H, const ushort* __restrict__ Wb,
    const float* __restrict__ bias, float* __restrict__ out) {
  __shared__ __align__(16) ushort As[BM][BK];        // 16 KB
  __shared__ __align__(16) ushort Bs[BN][BK];        // 16 KB

  const int tid  = threadIdx.x;
  const int lane = tid & 63;
  const int wid  = tid >> 6;                         // 0..3
  const int wm   = wid >> 1, wn = wid & 1;           // 2x2 wave grid, 64x64 each
  const int mb   = blockIdx.y, nb = blockIdx.x;

  floatx4 acc[4][4];
  #pragma unroll
  for (int i = 0; i < 4; ++i)
    #pragma unroll
    for (int j = 0; j < 4; ++j) acc[i][j] = (floatx4)(0.0f);

  // staging addresses: wave wid loads rows [wid*32, wid*32+32) of both tiles.
  // global_load_lds: LDS dest = uniform base + lane*16B; row = +lane>>3, kbytes = (lane&7)*16.
  const int l7 = lane & 7, l8 = lane >> 3;
  const size_t gA0 = (size_t)(mb * BM + wid * 32 + l8) * D_ + l7 * 8;
  const size_t gB0 = (size_t)(nb * BN + wid * 32 + l8) * D_ + l7 * 8;

  for (int t = 0; t < D_ / BK; ++t) {                // 10 K-steps
    const int k0 = t * BK;
    #pragma unroll
    for (int c = 0; c < 4; ++c) {
      __builtin_amdgcn_global_load_lds(
          (const __attribute__((address_space(1))) void*)(H + gA0 + c * 8 * D_ + k0),
          (__attribute__((address_space(3))) void*)(&As[wid * 32 + c * 8][0]),
          16, 0, 0);
      __builtin_amdgcn_global_load_lds(
          (const __attribute__((address_space(1))) void*)(Wb + gB0 + c * 8 * D_ + k0),
          (__attribute__((address_space(3))) void*)(&Bs[wid * 32 + c * 8][0]),
          16, 0, 0);
    }
    __syncthreads();                                 // compiler drains vmcnt before barrier

    #pragma unroll
    for (int kk = 0; kk < BK; kk += 32) {
      bf16x8 a[4], b[4];
      #pragma unroll
      for (int f = 0; f < 4; ++f) {
        a[f] = *(const bf16x8*)&As[wm * 64 + f * 16 + (lane & 15)][kk + (lane >> 4) * 8];
        b[f] = *(const bf16x8*)&Bs[wn * 64 + f * 16 + (lane & 15)][kk + (lane >> 4) * 8];
      }
      #pragma unroll
      for (int fm = 0; fm < 4; ++fm)
        #pragma unroll
        for (int fn = 0; fn < 4; ++fn)
          acc[fm][fn] = __builtin_amdgcn_mfma_f32_16x16x32_bf16(a[fm], b[fn], acc[fm][fn], 0, 0, 0);
    }
    __syncthreads();
  }

  // epilogue: C/D layout (m89): col = lane&15, row = (lane>>4)*4 + i
  const int col0 = nb * BN + wn * 64 + (lane & 15);
  float bv[4];
  #pragma unroll
  for (int fn = 0; fn < 4; ++fn) bv[fn] = bias[col0 + fn * 16];
  #pragma unroll
  for (int fm = 0; fm < 4; ++fm) {
    const int r0 = mb * BM + wm * 64 + fm * 16 + (lane >> 4) * 4;
    #pragma unroll
    for (int i = 0; i < 4; ++i) {
      float* orow = out + (size_t)(r0 + i) * V_;
      #pragma unroll
      for (int fn = 0; fn < 4; ++fn)
        orow[col0 + fn * 16] = acc[fm][fn][i] + bv[fn];
    }
  }
}

// ---- fallback (ws too small): fp32, one m-row + 256 v per block ----
__global__ void fallback_k(const float* __restrict__ enc, const float* __restrict__ pred,
                           const float* __restrict__ W, const float* __restrict__ bias,
                           float* __restrict__ out) {
  const int bid = blockIdx.x;
  const int m = bid >> 4;
  const int v = ((bid & 15) << 8) + threadIdx.x;
  __shared__ float h[D_];
  const int re = m >> 6;
  const int rp = ((m >> 14) << 6) | (m & 63);
  for (int d = threadIdx.x; d < D_; d += 256)
    h[d] = tanh_fast(enc[(size_t)re * D_ + d] + pred[(size_t)rp * D_ + d]);
  __syncthreads();
  const float* wr = W + (size_t)v * D_;
  float acc = bias[v];
  for (int d = 0; d < D_; d += 4) {
    float4 wv = *(const float4*)(wr + d);
    acc += h[d] * wv.x + h[d + 1] * wv.y + h[d + 2] * wv.z + h[d + 3] * wv.w;
  }
  out[(size_t)m * V_ + v] = acc;
}

extern "C" void kernel_launch(void* const* d_in, const int* in_sizes, int n_in,
                              void* d_out, int out_size, void* d_ws, size_t ws_size,
                              hipStream_t stream) {
  const float* enc  = (const float*)d_in[0];
  const float* pred = (const float*)d_in[1];
  const float* W    = (const float*)d_in[2];
  const float* bias = (const float*)d_in[3];
  float* out = (float*)d_out;

  const size_t needW = (size_t)V_ * D_ * sizeof(ushort);   //  5,242,880 B
  const size_t needH = (size_t)M_ * D_ * sizeof(ushort);   // 83,886,080 B

  if (ws_size >= needW + needH) {
    ushort* Wb = (ushort*)d_ws;
    ushort* Hb = (ushort*)((char*)d_ws + needW);
    cvt_w <<<dim3((V_ * D_ / 4) / 256), dim3(256), 0, stream>>>(W, Wb);
    make_h<<<dim3((M_ * D_ / 4) / 256), dim3(256), 0, stream>>>(enc, pred, Hb);
    gemm_bt<<<dim3(V_ / BN, M_ / BM), dim3(256), 0, stream>>>(Hb, Wb, bias, out);
  } else {
    fallback_k<<<dim3(M_ * 16), dim3(256), 0, stream>>>(enc, pred, W, bias, out);
  }
}